// Round 8
// baseline (320.416 us; speedup 1.0000x reference)
//
#include <hip/hip_runtime.h>
#include <math.h>

#define TOK 8192   // B*S tokens
#define DIM 256    // hidden
#define NE  32     // experts
#define NK  4      // top-k
#define NF  1024   // ffn dim

typedef __bf16 bf16x8 __attribute__((ext_vector_type(8)));
typedef float  f32x4  __attribute__((ext_vector_type(4)));
typedef unsigned short u16x8 __attribute__((ext_vector_type(8)));

__device__ __forceinline__ unsigned short f2b(float f) {
  unsigned u = __builtin_bit_cast(unsigned, f);
  unsigned r = (u + 0x7FFFu + ((u >> 16) & 1u)) >> 16;   // RNE
  return (unsigned short)r;
}

// async global->LDS, 16B per lane (linear LDS dest = wave-uniform base + lane*16)
__device__ __forceinline__ void gload16(const void* g, void* l) {
  __builtin_amdgcn_global_load_lds(
      (const __attribute__((address_space(1))) void*)g,
      (__attribute__((address_space(3))) void*)l, 16, 0, 0);
}

// ---------------- Router body (fp32, exact top-k match) + out zeroing ----------------
__device__ __forceinline__ void router_body(
    int bid, const float* __restrict__ x, const float* __restrict__ rw,
    int* __restrict__ counts, float* __restrict__ psum,
    int* __restrict__ etok, float* __restrict__ ewt,
    float* __restrict__ outz)
{
  __shared__ float xs[32][DIM + 4];
  __shared__ float ws[NE][DIM + 4];
  __shared__ float lg[32][NE];
  __shared__ int hist[NE];
  __shared__ int base[NE];

  const int tid = threadIdx.x;
  const int t0 = bid * 32;

  {
    float4 z4 = {0.f, 0.f, 0.f, 0.f};
    float4* og = (float4*)(outz + (size_t)t0 * DIM);
    #pragma unroll
    for (int i = 0; i < 8; i++) og[i*256 + tid] = z4;
  }

  {
    const float4* xg = (const float4*)(x + (size_t)t0 * DIM);
    for (int i = tid; i < 32 * (DIM/4); i += 256) {
      int t = i / (DIM/4), c = i % (DIM/4);
      *(float4*)&xs[t][c*4] = xg[t*(DIM/4)+c];
    }
    const float4* wgp = (const float4*)rw;
    for (int i = tid; i < NE * (DIM/4); i += 256) {
      int e = i / (DIM/4), c = i % (DIM/4);
      *(float4*)&ws[e][c*4] = wgp[e*(DIM/4)+c];
    }
  }
  if (tid < NE) hist[tid] = 0;
  __syncthreads();

  for (int i = 0; i < 4; i++) {
    int idx = i*256 + tid;
    int t = idx >> 5, e = idx & 31;
    float acc = 0.f;
    for (int c = 0; c < DIM/4; c++) {
      float4 a = *(const float4*)&xs[t][c*4];
      float4 b = *(const float4*)&ws[e][c*4];
      acc += a.x*b.x + a.y*b.y + a.z*b.z + a.w*b.w;
    }
    lg[t][e] = acc;
  }
  __syncthreads();

  int ids[NK]; int slots[NK]; float wts[NK];
  if (tid < 32) {
    const int t = tid;
    float l[NE];
    #pragma unroll
    for (int e = 0; e < NE; e++) l[e] = lg[t][e];
    unsigned mask = 0;
    float vals[NK];
    #pragma unroll
    for (int k = 0; k < NK; k++) {
      float best = -INFINITY; int bi = 0;
      for (int e = 0; e < NE; e++)
        if (!((mask >> e) & 1u) && l[e] > best) { best = l[e]; bi = e; }
      mask |= 1u << bi; vals[k] = best; ids[k] = bi;
    }
    float s4 = 0.f;
    #pragma unroll
    for (int k = 0; k < NK; k++) { wts[k] = __expf(vals[k] - vals[0]); s4 += wts[k]; }
    #pragma unroll
    for (int k = 0; k < NK; k++) wts[k] /= s4;
    float s = 0.f;
    for (int e = 0; e < NE; e++) { l[e] = __expf(l[e] - vals[0]); s += l[e]; }
    float inv = 1.f / s;
    for (int e = 0; e < NE; e++) lg[t][e] = l[e] * inv;
    #pragma unroll
    for (int k = 0; k < NK; k++) slots[k] = atomicAdd(&hist[ids[k]], 1);
  }
  __syncthreads();
  if (tid < NE) {
    float s = 0.f;
    for (int t = 0; t < 32; t++) s += lg[t][tid];
    atomicAdd(&psum[tid], s);
    int h = hist[tid];
    base[tid] = h ? atomicAdd(&counts[tid], h) : 0;
  }
  __syncthreads();
  if (tid < 32) {
    #pragma unroll
    for (int k = 0; k < NK; k++) {
      int p = base[ids[k]] + slots[k];
      etok[(size_t)ids[k]*TOK + p] = t0 + tid;
      ewt [(size_t)ids[k]*TOK + p] = wts[k];
    }
  }
}

// ---------------- Weight convert body: fp32 -> bf16, 16KB stages, pre-swizzled ------
// Per expert e, 96 stages of 16KB (8192 bf16), order G0,U0,D0,G1,... (32 chunks of 32f)
// G/U stage: elem(f 0..31, k=gk*8+j)   at f*256 + ((gk^(f&7))<<3)+j
// D   stage: elem(d 0..255, kf=fg*8+j) at d*32  + ((fg^((d>>1)&3))<<3)+j
//   (key (d>>1)&3, NOT (d&3): 64B rows span 16 banks; even rows need the key to
//    cycle all 4 groups across d=0,2,4..14 for balanced banks — (d&3) gave 2.9x conflicts)
__device__ __forceinline__ void convert_body(
    int gid, const float* __restrict__ wg_, const float* __restrict__ wu_,
    const float* __restrict__ wd_, unsigned short* __restrict__ wB)
{
  int sg  = gid >> 10;                        // global stage 0 .. E*96-1
  int idx = gid & 1023;
  int e   = sg / 96;
  int st  = sg - e * 96;
  int ch  = st / 3;                           // 0..31
  int ty  = st - ch * 3;                      // 0=G 1=U 2=D
  unsigned short* dst = wB + ((size_t)sg << 13);
  const float* src;
  int pos;
  if (ty < 2) {
    int f = idx >> 5, gk = idx & 31;          // f 0..31
    const float* w = (ty == 0) ? wg_ : wu_;
    src = w + (size_t)e * (NF*DIM) + (size_t)(ch*32 + f) * DIM + (gk << 3);
    pos = f*256 + ((gk ^ (f & 7)) << 3);
  } else {
    int d = idx >> 2, fg = idx & 3;           // d 0..255, fg 0..3
    src = wd_ + (size_t)e * (DIM*NF) + (size_t)d * NF + (ch << 5) + (fg << 3);
    pos = (d << 5) + ((fg ^ ((d >> 1) & 3)) << 3);
  }
  float4 a = *(const float4*)src;
  float4 c = *(const float4*)(src + 4);
  u16x8 v;
  v[0]=f2b(a.x); v[1]=f2b(a.y); v[2]=f2b(a.z); v[3]=f2b(a.w);
  v[4]=f2b(c.x); v[5]=f2b(c.y); v[6]=f2b(c.z); v[7]=f2b(c.w);
  *(u16x8*)&dst[pos] = v;
}

// ---------------- Fused router || convert (independent work, one dispatch) --------
// blocks 0..255: router; blocks 256..12543: convert, ONE granule per thread
// (no unrolled loop: keeps VGPR low -> full occupancy on the streaming part;
//  v10's unroll-8 hit 256 VGPR and ran at 1.3 TB/s)
__global__ __launch_bounds__(256) void fused_rc_kernel(
    const float* __restrict__ x, const float* __restrict__ rw,
    const float* __restrict__ wg_, const float* __restrict__ wu_,
    const float* __restrict__ wd_,
    int* __restrict__ counts, float* __restrict__ psum,
    int* __restrict__ etok, float* __restrict__ ewt,
    float* __restrict__ outz, unsigned short* __restrict__ wB)
{
  if (blockIdx.x < 256) {
    router_body(blockIdx.x, x, rw, counts, psum, etok, ewt, outz);
  } else {
    int gid = (blockIdx.x - 256) * 256 + threadIdx.x;   // 12288*256 = 32*96*1024
    convert_body(gid, wg_, wu_, wd_, wB);
  }
}

// ---------------- Standalone router (fallback path) ----------------
__global__ __launch_bounds__(256) void router_kernel(
    const float* __restrict__ x, const float* __restrict__ rw,
    int* __restrict__ counts, float* __restrict__ psum,
    int* __restrict__ etok, float* __restrict__ ewt,
    float* __restrict__ outz)
{
  router_body(blockIdx.x, x, rw, counts, psum, etok, ewt, outz);
}

// ---------------- Aux loss ----------------
__global__ void aux_kernel(const int* __restrict__ counts,
                           const float* __restrict__ psum,
                           float* __restrict__ aux_out)
{
  int tid = threadIdx.x;
  float v = 0.f;
  if (tid < NE) v = (counts[tid] / (float)TOK) * (psum[tid] / (float)TOK);
  #pragma unroll
  for (int off = 32; off; off >>= 1) v += __shfl_down(v, off);
  if (tid == 0) aux_out[0] = (float)NE * v;
}

// ========== Expert FFN v11: v10 + balanced swizzle keys ==========
// 64-tok tiles, 16KB stages, 2 blocks/CU (proven v10). Swizzle keys for the
// 64B-row D stage and hs changed (d&3)->((d>>1)&3): balances banks for b128
// reads (v10's key repeated with the row-parity period -> 4-way conflicts).
#define PWB(N) asm volatile("s_waitcnt vmcnt(" #N ") lgkmcnt(0)\n\ts_barrier" ::: "memory")

#define ISSUE_L(sl_) do {                                               \
    const unsigned short* sp_ = wE + ((size_t)(3*c0 + (sl_)) << 13);    \
    unsigned short* dp_ = &ring[(sl_) & 3][0];                          \
    _Pragma("unroll")                                                   \
    for (int i_ = 0; i_ < 2; i_++) {                                    \
      int o_ = (i_*512 + tid) << 3;                                     \
      gload16(sp_ + o_, dp_ + o_);                                      \
    }                                                                   \
  } while (0)

#define COMP_G(rs)                                                      \
  { const int fl = nw*16 + ln;                                          \
    const int rowb = fl*256, xo = fl & 7;                               \
    ga = (f32x4){0,0,0,0};                                              \
    _Pragma("unroll")                                                   \
    for (int kk = 0; kk < 8; kk++) {                                    \
      bf16x8 bg = *(const bf16x8*)&rs[rowb + (((kk*4 + q) ^ xo) << 3)]; \
      ga = __builtin_amdgcn_mfma_f32_16x16x32_bf16(xf[kk], bg, ga, 0,0,0); \
    } }

#define COMP_U(rs)                                                      \
  { const int fl = nw*16 + ln;                                          \
    const int rowb = fl*256, xo = fl & 7;                               \
    f32x4 ua = (f32x4){0,0,0,0};                                        \
    _Pragma("unroll")                                                   \
    for (int kk = 0; kk < 8; kk++) {                                    \
      bf16x8 bu = *(const bf16x8*)&rs[rowb + (((kk*4 + q) ^ xo) << 3)]; \
      ua = __builtin_amdgcn_mfma_f32_16x16x32_bf16(xf[kk], bu, ua, 0,0,0); \
    }                                                                   \
    const int fu = fl >> 3, f7 = fl & 7;                                \
    _Pragma("unroll")                                                   \
    for (int rr = 0; rr < 4; rr++) {                                    \
      const int row = mw*16 + q*4 + rr;                                 \
      float g0 = ga[rr];                                                \
      hs[row*32 + (((fu ^ ((row >> 1) & 3)) << 3) | f7)] =              \
          f2b((g0 / (1.f + __expf(-g0))) * ua[rr]);                     \
    } }

#define COMP_D(rs)                                                      \
  { const int arow = mw*16 + ln;                                        \
    bf16x8 a = *(const bf16x8*)&hs[arow*32 + ((q ^ ((arow >> 1) & 3)) << 3)]; \
    _Pragma("unroll")                                                   \
    for (int nt = 0; nt < 8; nt++) {                                    \
      const int d = nw*128 + nt*16 + ln;                                \
      bf16x8 bd = *(const bf16x8*)&rs[d*32 + ((q ^ ((d >> 1) & 3)) << 3)]; \
      oacc[nt] = __builtin_amdgcn_mfma_f32_16x16x32_bf16(a, bd, oacc[nt], 0,0,0); \
    } }

__global__ __launch_bounds__(512, 4) void expert_mfma11_kernel(
    const float* __restrict__ x,
    const unsigned short* __restrict__ wB,
    const int* __restrict__ counts,
    const int* __restrict__ etok, const float* __restrict__ ewt,
    float* __restrict__ out)
{
  __shared__ unsigned short ring[4][8192];   // 4 x 16 KB bf16 stage ring
  __shared__ unsigned short hs[2048];        // 4 KB H tile [64 tok][32 f], XOR-swz
  __shared__ int   lel[64];
  __shared__ float lwt[64];
  __shared__ int   pfx[NE + 1];              // tile prefix sums

  const int tid  = threadIdx.x;
  const int lane = tid & 63;
  const int wv   = tid >> 6;
  const int mw   = wv & 3;      // token quarter (16 tokens)
  const int nw   = wv >> 2;     // f-half (16 f) / d-half (128 d)
  const int q    = lane >> 4;
  const int ln   = lane & 15;

  if (tid == 0) {
    int acc = 0;
    #pragma unroll 1
    for (int e = 0; e < NE; e++) { pfx[e] = acc; acc += (counts[e] + 63) >> 6; }
    pfx[NE] = acc;
  }
  __syncthreads();

  // all scheduling scalars forced to SGPR: barriers stay in scalar control flow
  const int U  = __builtin_amdgcn_readfirstlane(pfx[NE] << 5);  // total chunk units
  const int ub = ((blockIdx.x & 7) << 6) | (blockIdx.x >> 3);   // XCD-contiguous (512)
  int       u  = (ub * U) >> 9;                                 // this block's range
  const int u1 = ((ub + 1) * U) >> 9;

  #pragma unroll 1
  while (u < u1) {
    // locate (expert, tile, chunk-range) for unit u
    const int g = u >> 5;                           // global tile id (scalar)
    int ev = 0;
    #pragma unroll 1
    while (pfx[ev + 1] <= g) ev++;
    const int e   = __builtin_amdgcn_readfirstlane(ev);
    const int t   = __builtin_amdgcn_readfirstlane(g - pfx[e]);
    const int c0  = u & 31;
    const int c1  = (32 < c0 + (u1 - u)) ? 32 : (c0 + (u1 - u));
    const int cnt = __builtin_amdgcn_readfirstlane(counts[e]);
    const int t0  = t << 6;
    const unsigned short* wE = wB + (size_t)e * 96 * 8192;
    const int*   el = etok + (size_t)e * TOK;
    const float* ew = ewt  + (size_t)e * TOK;

    if (tid < 64) {
      int gt = t0 + tid;
      lel[tid] = (gt < cnt) ? el[gt] : -1;
      lwt[tid] = (gt < cnt) ? ew[gt] : 0.f;
    }
    __syncthreads();

    // A-fragments: 16 tokens x K=256 in registers (fp32->bf16), 32 VGPR
    bf16x8 xf[8];
    {
      int row = mw*16 + ln;
      int tok = lel[row]; if (tok < 0) tok = 0;
      const float* xr = x + (size_t)tok * DIM;
      #pragma unroll
      for (int k = 0; k < 8; k++) {
        float4 a = *(const float4*)(xr + k*32 + q*8);
        float4 c = *(const float4*)(xr + k*32 + q*8 + 4);
        union { bf16x8 v; unsigned short s[8]; } tt;
        tt.s[0]=f2b(a.x); tt.s[1]=f2b(a.y); tt.s[2]=f2b(a.z); tt.s[3]=f2b(a.w);
        tt.s[4]=f2b(c.x); tt.s[5]=f2b(c.y); tt.s[6]=f2b(c.z); tt.s[7]=f2b(c.w);
        xf[k] = tt.v;
      }
    }

    f32x4 oacc[8];
    #pragma unroll
    for (int nt = 0; nt < 8; nt++) oacc[nt] = (f32x4){0,0,0,0};

    const int S = 3 * (c1 - c0);    // stages this segment (>= 3, scalar)

    // pin the vmcnt baseline (xf loads fully retired), then prime the ring:
    // 3 stages = 6 loads in flight
    asm volatile("s_waitcnt vmcnt(0)" ::: "memory");
    ISSUE_L(0); ISSUE_L(1); ISSUE_L(2);

    f32x4 ga;

    #pragma unroll 1
    for (int c = c0; c < c1; c++) {
      const int sb = 3 * (c - c0);
      // barrier A: stages sb (G), sb+1 (U) arrived; c.D (2 loads) stays in flight
      PWB(2);
      if (sb + 3 < S) ISSUE_L(sb + 3);          // (c+1).G -> slot of (c-1).D
      { const unsigned short* rs = ring[ sb      & 3]; COMP_G(rs); }
      { const unsigned short* rs = ring[(sb + 1) & 3]; COMP_U(rs); }
      // barrier B: stage sb+2 (D) arrived + hs writes visible
      if (sb + 3 < S) {
        PWB(2);                                  // (c+1).G stays in flight
        ISSUE_L(sb + 4);                         // (c+1).U -> slot of c.G
        ISSUE_L(sb + 5);                         // (c+1).D -> slot of c.U
      } else {
        PWB(0);                                  // tail drain
      }
      { const unsigned short* rs = ring[(sb + 2) & 3]; COMP_D(rs); }
    }

    // partial-tile weighted atomic scatter
    #pragma unroll
    for (int nt = 0; nt < 8; nt++) {
      int d = nw*128 + nt*16 + ln;
      #pragma unroll
      for (int rr = 0; rr < 4; rr++) {
        int tl = mw*16 + q*4 + rr;
        int tok = lel[tl];
        if (tok >= 0)
          atomicAdd(&out[(size_t)tok*DIM + d], lwt[tl] * oacc[nt][rr]);
      }
    }
    __syncthreads();   // protect lel/lwt/ring/hs before next segment

    u += c1 - c0;
  }
}

// ========== Fallback expert kernel (fp32 weights, on-the-fly convert) ==========
__global__ __launch_bounds__(512, 2) void expert_mfma5_kernel(
    const float* __restrict__ x,
    const float* __restrict__ wg_, const float* __restrict__ wu_,
    const float* __restrict__ wd_,
    const int* __restrict__ counts,
    const int* __restrict__ etok, const float* __restrict__ ewt,
    float* __restrict__ out)
{
  const int b  = blockIdx.x;
  const int j  = b >> 3;
  const int e  = (b & 7) + 8 * (j & 3);
  const int s0 = j >> 2;
  const int cnt = counts[e];

  __shared__ unsigned short stg[2][16384];
  __shared__ unsigned short hsf[128][72];
  __shared__ int   lel[128];
  __shared__ float lwt[128];

  const int tid  = threadIdx.x;
  const int lane = tid & 63;
  const int wv   = tid >> 6;
  const int mw   = wv & 3;
  const int nw   = wv >> 2;
  const int q    = lane >> 4;
  const int ln   = lane & 15;

  int guOff[4], dOff[4], dRow[4], dFg[4];
  #pragma unroll
  for (int i = 0; i < 4; i++) {
    int G = i*512 + tid;
    int f = G >> 5, gk = G & 31;
    guOff[i] = f*256 + ((gk ^ (f & 7)) << 3);
    int d = G >> 3, fg = G & 7;
    dOff[i] = d*64 + ((fg ^ (d & 7)) << 3);
    dRow[i] = d; dFg[i] = fg;
  }

  const float* wgE = wg_ + (size_t)e * NF * DIM;
  const float* wuE = wu_ + (size_t)e * NF * DIM;
  const float* wdE = wd_ + (size_t)e * DIM * NF;

  const int*   el = etok + (size_t)e * TOK;
  const float* ew = ewt  + (size_t)e * TOK;

  for (int t0 = s0 * 128; t0 < cnt; t0 += 1024) {
    if (tid < 128) {
      int gt = t0 + tid;
      lel[tid] = (gt < cnt) ? el[gt] : -1;
      lwt[tid] = (gt < cnt) ? ew[gt] : 0.f;
    }
    __syncthreads();

    bf16x8 xf[2][8];
    #pragma unroll
    for (int m = 0; m < 2; m++) {
      int row = mw*32 + m*16 + ln;
      int tok = lel[row]; if (tok < 0) tok = 0;
      const float* xr = x + (size_t)tok * DIM;
      #pragma unroll
      for (int k = 0; k < 8; k++) {
        float4 a = *(const float4*)(xr + k*32 + q*8);
        float4 c = *(const float4*)(xr + k*32 + q*8 + 4);
        union { bf16x8 v; unsigned short s[8]; } t;
        t.s[0]=f2b(a.x); t.s[1]=f2b(a.y); t.s[2]=f2b(a.z); t.s[3]=f2b(a.w);
        t.s[4]=f2b(c.x); t.s[5]=f2b(c.y); t.s[6]=f2b(c.z); t.s[7]=f2b(c.w);
        xf[m][k] = t.v;
      }
    }

    f32x4 oacc[8][2];
    #pragma unroll
    for (int nt = 0; nt < 8; nt++) { oacc[nt][0] = (f32x4){0,0,0,0}; oacc[nt][1] = (f32x4){0,0,0,0}; }

    unsigned short* pA = stg[0];
    unsigned short* pB = stg[1];
    float4 r[8];

    {
      const float4* s4 = (const float4*)wgE;
      #pragma unroll
      for (int i = 0; i < 4; i++) { int G = i*512 + tid; r[2*i] = s4[2*G]; r[2*i+1] = s4[2*G+1]; }
      #pragma unroll
      for (int i = 0; i < 4; i++) {
        u16x8 v;
        v[0]=f2b(r[2*i].x);   v[1]=f2b(r[2*i].y);   v[2]=f2b(r[2*i].z);   v[3]=f2b(r[2*i].w);
        v[4]=f2b(r[2*i+1].x); v[5]=f2b(r[2*i+1].y); v[6]=f2b(r[2*i+1].z); v[7]=f2b(r[2*i+1].w);
        *(u16x8*)&pA[guOff[i]] = v;
      }
    }
    __syncthreads();

    f32x4 ga[2][2];

    for (int ch = 0; ch < 16; ch++) {
      {
        const float4* s4 = (const float4*)(wuE + (size_t)ch*16384);
        #pragma unroll
        for (int i = 0; i < 4; i++) { int G = i*512 + tid; r[2*i] = s4[2*G]; r[2*i+1] = s4[2*G+1]; }
      }
      #pragma unroll
      for (int nt = 0; nt < 2; nt++) {
        int fl = nw*32 + nt*16 + ln;
        int rowb = fl*256, xo = fl & 7;
        ga[nt][0] = (f32x4){0,0,0,0}; ga[nt][1] = (f32x4){0,0,0,0};
        #pragma unroll
        for (int kk = 0; kk < 8; kk++) {
          bf16x8 bg = *(const bf16x8*)&pA[rowb + (((kk*4 + q) ^ xo) << 3)];
          ga[nt][0] = __builtin_amdgcn_mfma_f32_16x16x32_bf16(xf[0][kk], bg, ga[nt][0], 0,0,0);
          ga[nt][1] = __builtin_amdgcn_mfma_f32_16x16x32_bf16(xf[1][kk], bg, ga[nt][1], 0,0,0);
        }
      }
      #pragma unroll
      for (int i = 0; i < 4; i++) {
        u16x8 v;
        v[0]=f2b(r[2*i].x);   v[1]=f2b(r[2*i].y);   v[2]=f2b(r[2*i].z);   v[3]=f2b(r[2*i].w);
        v[4]=f2b(r[2*i+1].x); v[5]=f2b(r[2*i+1].y); v[6]=f2b(r[2*i+1].z); v[7]=f2b(r[2*i+1].w);
        *(u16x8*)&pB[guOff[i]] = v;
      }
      __syncthreads();
      { unsigned short* t = pA; pA = pB; pB = t; }

      {
        #pragma unroll
        for (int i = 0; i < 4; i++) {
          const float4* p = (const float4*)(wdE + (size_t)dRow[i]*NF + ch*64 + dFg[i]*8);
          r[2*i] = p[0]; r[2*i+1] = p[1];
        }
      }
      #pragma unroll
      for (int nt = 0; nt < 2; nt++) {
        int fl = nw*32 + nt*16 + ln;
        int rowb = fl*256, xo = fl & 7;
        f32x4 ua0 = (f32x4){0,0,0,0}, ua1 = (f32x4){0,0,0,0};
        #pragma unroll
        for (int kk = 0; kk < 8; kk++) {
          bf16x8 bu = *(const bf16x8*)&pA[rowb + (((kk*4 + q) ^ xo) << 3)];
          ua0 = __builtin_amdgcn_mfma_f32_16x16x32_bf16(xf[0][kk], bu, ua0, 0,0,0);
          ua1 = __builtin_amdgcn_mfma_f32_16x16x32_bf16(xf[1][kk], bu, ua1, 0,0,0);
        }
        #pragma unroll
        for (int rr = 0; rr < 4; rr++) {
          float g0 = ga[nt][0][rr], g1 = ga[nt][1][rr];
          hsf[mw*32      + q*4 + rr][fl] = f2b((g0 / (1.f + __expf(-g0))) * ua0[rr]);
          hsf[mw*32 + 16 + q*4 + rr][fl] = f2b((g1 / (1.f + __expf(-g1))) * ua1[rr]);
        }
      }
      #pragma unroll
      for (int i = 0; i < 4; i++) {
        u16x8 v;
        v[0]=f2b(r[2*i].x);   v[1]=f2b(r[2*i].y);   v[2]=f2b(r[2*i].z);   v[3]=f2b(r[2*i].w);
        v[4]=f2b(r[2*i+1].x); v[5]=f2b(r[2*i+1].y); v[6]=f2b(r[2*i+1].z); v[7]=f2b(r[2*i+1].w);
        *(u16x8*)&pB[dOff[i]] = v;
      }
      __syncthreads();
      { unsigned short* t = pA; pA = pB; pB = t; }

      if (ch < 15) {
        const float4* s4 = (const float4*)(wgE + (size_t)(ch+1)*16384);
        #pragma unroll
        for (int i = 0; i < 4; i++) { int G = i*512 + tid; r[2*i] = s4[2*G]; r[2*i+1] = s4[2*G+1]; }
      }
      #pragma unroll
      for (int kk = 0; kk < 2; kk++) {
        bf16x8 a0 = *(const bf16x8*)&hsf[mw*32      + ln][kk*32 + q*8];
        bf16x8 a1 = *(const bf16x8*)&hsf[mw*32 + 16 + ln][kk*32 + q*8];
        #pragma unroll
        for (int nt = 0; nt < 8; nt++) {
          int d = nw*128 + nt*16 + ln;
          bf16x8 bd = *(const bf16x8*)&pA[d*64 + (((kk*4 + q) ^ (d & 7)) << 3)];
          oacc[nt][0] = __builtin_amdgcn_mfma_f32_16x16x32_bf16(a0, bd, oacc[nt][0], 0,0,0);
          oacc[nt][1] = __builtin_amdgcn_mfma_f32_16x16x32_bf16(a1, bd, oacc[nt][1], 0,0,0);
        }
      }
      if (ch < 15) {
        #pragma unroll
        for (int i = 0; i < 4; i++) {
          u16x8 v;
          v[0]=f2b(r[2*i].x);   v[1]=f2b(r[2*i].y);   v[2]=f2b(r[2*i].z);   v[3]=f2b(r[2*i].w);
          v[4]=f2b(r[2*i+1].x); v[5]=f2b(r[2*i+1].y); v[6]=f2b(r[2*i+1].z); v[7]=f2b(r[2*i+1].w);
          *(u16x8*)&pB[guOff[i]] = v;
        }
      }
      __syncthreads();
      { unsigned short* t = pA; pA = pB; pB = t; }
    }

    #pragma unroll
    for (int nt = 0; nt < 8; nt++) {
      int d = nw*128 + nt*16 + ln;
      #pragma unroll
      for (int m = 0; m < 2; m++)
        #pragma unroll
        for (int rr = 0; rr < 4; rr++) {
          int tl = mw*32 + m*16 + q*4 + rr;
          int tok = lel[tl];
          if (tok >= 0)
            atomicAdd(&out[(size_t)tok*DIM + d], lwt[tl] * oacc[nt][m][rr]);
        }
    }
    __syncthreads();
  }
}

extern "C" void kernel_launch(void* const* d_in, const int* in_sizes, int n_in,
                              void* d_out, int out_size, void* d_ws, size_t ws_size,
                              hipStream_t stream)
{
  const float* x  = (const float*)d_in[0];
  const float* rw = (const float*)d_in[1];
  const float* wg = (const float*)d_in[2];
  const float* wu = (const float*)d_in[3];
  const float* wd = (const float*)d_in[4];
  float* out = (float*)d_out;

  // ws layout: counts[32] | psum[32] | etok[E*T] | ewt[E*T] | ... | wB (48MB @ 4MB)
  int*   counts = (int*)d_ws;
  float* psum   = (float*)((char*)d_ws + 128);
  int*   etok   = (int*)((char*)d_ws + 256);
  float* ewt    = (float*)((char*)d_ws + 256 + (size_t)NE*TOK*4);

  hipMemsetAsync(d_ws, 0, 256, stream);

  const size_t wboff = (size_t)4 << 20;
  const size_t wbsz  = (size_t)NE * 96 * 8192 * 2;   // 48 MB
  if (ws_size >= wboff + wbsz) {
    unsigned short* wB = (unsigned short*)((char*)d_ws + wboff);
    fused_rc_kernel<<<256 + 12288, 256, 0, stream>>>(
        x, rw, wg, wu, wd, counts, psum, etok, ewt, out, wB);
    aux_kernel<<<1, 64, 0, stream>>>(counts, psum, out + (size_t)TOK*DIM);
    expert_mfma11_kernel<<<512, 512, 0, stream>>>(x, wB, counts, etok, ewt, out);
  } else {
    router_kernel<<<TOK/32, 256, 0, stream>>>(x, rw, counts, psum, etok, ewt, out);
    aux_kernel<<<1, 64, 0, stream>>>(counts, psum, out + (size_t)TOK*DIM);
    expert_mfma5_kernel<<<256, 512, 0, stream>>>(x, wg, wu, wd, counts, etok, ewt, out);
  }
}

// Round 9
// 298.340 us; speedup vs baseline: 1.0740x; 1.0740x over previous
//
#include <hip/hip_runtime.h>
#include <math.h>

#define TOK 8192   // B*S tokens
#define DIM 256    // hidden
#define NE  32     // experts
#define NK  4      // top-k
#define NF  1024   // ffn dim

typedef __bf16 bf16x8 __attribute__((ext_vector_type(8)));
typedef float  f32x4  __attribute__((ext_vector_type(4)));
typedef unsigned short u16x8 __attribute__((ext_vector_type(8)));

__device__ __forceinline__ unsigned short f2b(float f) {
  unsigned u = __builtin_bit_cast(unsigned, f);
  unsigned r = (u + 0x7FFFu + ((u >> 16) & 1u)) >> 16;   // RNE
  return (unsigned short)r;
}

// async global->LDS, 16B per lane (linear LDS dest = wave-uniform base + lane*16)
__device__ __forceinline__ void gload16(const void* g, void* l) {
  __builtin_amdgcn_global_load_lds(
      (const __attribute__((address_space(1))) void*)g,
      (__attribute__((address_space(3))) void*)l, 16, 0, 0);
}

// ---------------- Router (fp32, exact top-k match) + out zeroing ----------------
// Standalone: its 69.5KB LDS / register pressure only costs its own 256 blocks.
// (Fusing this with convert charged these resources to 12k streaming blocks ->
//  VGPR 256 + LDS 71KB on the convert path -> 1.27 TB/s. De-fused.)
__global__ __launch_bounds__(256) void router_kernel(
    const float* __restrict__ x, const float* __restrict__ rw,
    int* __restrict__ counts, float* __restrict__ psum,
    int* __restrict__ etok, float* __restrict__ ewt,
    float* __restrict__ outz)
{
  __shared__ float xs[32][DIM + 4];
  __shared__ float ws[NE][DIM + 4];
  __shared__ float lg[32][NE];
  __shared__ int hist[NE];
  __shared__ int base[NE];

  const int tid = threadIdx.x;
  const int t0 = blockIdx.x * 32;

  {
    float4 z4 = {0.f, 0.f, 0.f, 0.f};
    float4* og = (float4*)(outz + (size_t)t0 * DIM);
    #pragma unroll
    for (int i = 0; i < 8; i++) og[i*256 + tid] = z4;
  }

  {
    const float4* xg = (const float4*)(x + (size_t)t0 * DIM);
    for (int i = tid; i < 32 * (DIM/4); i += 256) {
      int t = i / (DIM/4), c = i % (DIM/4);
      *(float4*)&xs[t][c*4] = xg[t*(DIM/4)+c];
    }
    const float4* wgp = (const float4*)rw;
    for (int i = tid; i < NE * (DIM/4); i += 256) {
      int e = i / (DIM/4), c = i % (DIM/4);
      *(float4*)&ws[e][c*4] = wgp[e*(DIM/4)+c];
    }
  }
  if (tid < NE) hist[tid] = 0;
  __syncthreads();

  for (int i = 0; i < 4; i++) {
    int idx = i*256 + tid;
    int t = idx >> 5, e = idx & 31;
    float acc = 0.f;
    for (int c = 0; c < DIM/4; c++) {
      float4 a = *(const float4*)&xs[t][c*4];
      float4 b = *(const float4*)&ws[e][c*4];
      acc += a.x*b.x + a.y*b.y + a.z*b.z + a.w*b.w;
    }
    lg[t][e] = acc;
  }
  __syncthreads();

  int ids[NK]; int slots[NK]; float wts[NK];
  if (tid < 32) {
    const int t = tid;
    float l[NE];
    #pragma unroll
    for (int e = 0; e < NE; e++) l[e] = lg[t][e];
    unsigned mask = 0;
    float vals[NK];
    #pragma unroll
    for (int k = 0; k < NK; k++) {
      float best = -INFINITY; int bi = 0;
      for (int e = 0; e < NE; e++)
        if (!((mask >> e) & 1u) && l[e] > best) { best = l[e]; bi = e; }
      mask |= 1u << bi; vals[k] = best; ids[k] = bi;
    }
    float s4 = 0.f;
    #pragma unroll
    for (int k = 0; k < NK; k++) { wts[k] = __expf(vals[k] - vals[0]); s4 += wts[k]; }
    #pragma unroll
    for (int k = 0; k < NK; k++) wts[k] /= s4;
    float s = 0.f;
    for (int e = 0; e < NE; e++) { l[e] = __expf(l[e] - vals[0]); s += l[e]; }
    float inv = 1.f / s;
    for (int e = 0; e < NE; e++) lg[t][e] = l[e] * inv;
    #pragma unroll
    for (int k = 0; k < NK; k++) slots[k] = atomicAdd(&hist[ids[k]], 1);
  }
  __syncthreads();
  if (tid < NE) {
    float s = 0.f;
    for (int t = 0; t < 32; t++) s += lg[t][tid];
    atomicAdd(&psum[tid], s);
    int h = hist[tid];
    base[tid] = h ? atomicAdd(&counts[tid], h) : 0;
  }
  __syncthreads();
  if (tid < 32) {
    #pragma unroll
    for (int k = 0; k < NK; k++) {
      int p = base[ids[k]] + slots[k];
      etok[(size_t)ids[k]*TOK + p] = t0 + tid;
      ewt [(size_t)ids[k]*TOK + p] = wts[k];
    }
  }
}

// ---------------- Weight convert: fp32 -> bf16, 16KB stages, pre-swizzled ------
// Standalone streaming kernel: NO LDS, low VGPR, grid-stride -> full occupancy.
// Per expert e, 96 stages of 16KB (8192 bf16), order G0,U0,D0,G1,... (32 chunks)
// G/U stage: elem(f 0..31, k=gk*8+j)   at f*256 + ((gk^(f&7))<<3)+j
// D   stage: elem(d 0..255, kf=fg*8+j) at d*32  + ((fg^((d>>1)&3))<<3)+j
#define CVT_TOTAL (NE * 96 * 1024)   // granules (8 bf16 each)
#define CVT_BLOCKS 2048

__global__ __launch_bounds__(256) void convert_kernel(
    const float* __restrict__ wg_, const float* __restrict__ wu_,
    const float* __restrict__ wd_, unsigned short* __restrict__ wB)
{
  int gid = blockIdx.x * 256 + threadIdx.x;
  #pragma unroll 1
  for (; gid < CVT_TOTAL; gid += CVT_BLOCKS * 256) {
    int sg  = gid >> 10;                        // global stage 0 .. E*96-1
    int idx = gid & 1023;
    int e   = sg / 96;
    int st  = sg - e * 96;
    int ch  = st / 3;                           // 0..31
    int ty  = st - ch * 3;                      // 0=G 1=U 2=D
    unsigned short* dst = wB + ((size_t)sg << 13);
    const float* src;
    int pos;
    if (ty < 2) {
      int f = idx >> 5, gk = idx & 31;          // f 0..31
      const float* w = (ty == 0) ? wg_ : wu_;
      src = w + (size_t)e * (NF*DIM) + (size_t)(ch*32 + f) * DIM + (gk << 3);
      pos = f*256 + ((gk ^ (f & 7)) << 3);
    } else {
      int d = idx >> 2, fg = idx & 3;           // d 0..255, fg 0..3
      src = wd_ + (size_t)e * (DIM*NF) + (size_t)d * NF + (ch << 5) + (fg << 3);
      pos = (d << 5) + ((fg ^ ((d >> 1) & 3)) << 3);
    }
    float4 a = *(const float4*)src;
    float4 c = *(const float4*)(src + 4);
    u16x8 v;
    v[0]=f2b(a.x); v[1]=f2b(a.y); v[2]=f2b(a.z); v[3]=f2b(a.w);
    v[4]=f2b(c.x); v[5]=f2b(c.y); v[6]=f2b(c.z); v[7]=f2b(c.w);
    *(u16x8*)&dst[pos] = v;
  }
}

// ---------------- Aux loss ----------------
__global__ void aux_kernel(const int* __restrict__ counts,
                           const float* __restrict__ psum,
                           float* __restrict__ aux_out)
{
  int tid = threadIdx.x;
  float v = 0.f;
  if (tid < NE) v = (counts[tid] / (float)TOK) * (psum[tid] / (float)TOK);
  #pragma unroll
  for (int off = 32; off; off >>= 1) v += __shfl_down(v, off);
  if (tid == 0) aux_out[0] = (float)NE * v;
}

// ========== Expert FFN v11 (unchanged from round 8): 64-tok tiles, 16KB stages,
// 2 blocks/CU, balanced swizzle keys ==========
#define PWB(N) asm volatile("s_waitcnt vmcnt(" #N ") lgkmcnt(0)\n\ts_barrier" ::: "memory")

#define ISSUE_L(sl_) do {                                               \
    const unsigned short* sp_ = wE + ((size_t)(3*c0 + (sl_)) << 13);    \
    unsigned short* dp_ = &ring[(sl_) & 3][0];                          \
    _Pragma("unroll")                                                   \
    for (int i_ = 0; i_ < 2; i_++) {                                    \
      int o_ = (i_*512 + tid) << 3;                                     \
      gload16(sp_ + o_, dp_ + o_);                                      \
    }                                                                   \
  } while (0)

#define COMP_G(rs)                                                      \
  { const int fl = nw*16 + ln;                                          \
    const int rowb = fl*256, xo = fl & 7;                               \
    ga = (f32x4){0,0,0,0};                                              \
    _Pragma("unroll")                                                   \
    for (int kk = 0; kk < 8; kk++) {                                    \
      bf16x8 bg = *(const bf16x8*)&rs[rowb + (((kk*4 + q) ^ xo) << 3)]; \
      ga = __builtin_amdgcn_mfma_f32_16x16x32_bf16(xf[kk], bg, ga, 0,0,0); \
    } }

#define COMP_U(rs)                                                      \
  { const int fl = nw*16 + ln;                                          \
    const int rowb = fl*256, xo = fl & 7;                               \
    f32x4 ua = (f32x4){0,0,0,0};                                        \
    _Pragma("unroll")                                                   \
    for (int kk = 0; kk < 8; kk++) {                                    \
      bf16x8 bu = *(const bf16x8*)&rs[rowb + (((kk*4 + q) ^ xo) << 3)]; \
      ua = __builtin_amdgcn_mfma_f32_16x16x32_bf16(xf[kk], bu, ua, 0,0,0); \
    }                                                                   \
    const int fu = fl >> 3, f7 = fl & 7;                                \
    _Pragma("unroll")                                                   \
    for (int rr = 0; rr < 4; rr++) {                                    \
      const int row = mw*16 + q*4 + rr;                                 \
      float g0 = ga[rr];                                                \
      hs[row*32 + (((fu ^ ((row >> 1) & 3)) << 3) | f7)] =              \
          f2b((g0 / (1.f + __expf(-g0))) * ua[rr]);                     \
    } }

#define COMP_D(rs)                                                      \
  { const int arow = mw*16 + ln;                                        \
    bf16x8 a = *(const bf16x8*)&hs[arow*32 + ((q ^ ((arow >> 1) & 3)) << 3)]; \
    _Pragma("unroll")                                                   \
    for (int nt = 0; nt < 8; nt++) {                                    \
      const int d = nw*128 + nt*16 + ln;                                \
      bf16x8 bd = *(const bf16x8*)&rs[d*32 + ((q ^ ((d >> 1) & 3)) << 3)]; \
      oacc[nt] = __builtin_amdgcn_mfma_f32_16x16x32_bf16(a, bd, oacc[nt], 0,0,0); \
    } }

__global__ __launch_bounds__(512, 4) void expert_mfma11_kernel(
    const float* __restrict__ x,
    const unsigned short* __restrict__ wB,
    const int* __restrict__ counts,
    const int* __restrict__ etok, const float* __restrict__ ewt,
    float* __restrict__ out)
{
  __shared__ unsigned short ring[4][8192];   // 4 x 16 KB bf16 stage ring
  __shared__ unsigned short hs[2048];        // 4 KB H tile [64 tok][32 f], XOR-swz
  __shared__ int   lel[64];
  __shared__ float lwt[64];
  __shared__ int   pfx[NE + 1];              // tile prefix sums

  const int tid  = threadIdx.x;
  const int lane = tid & 63;
  const int wv   = tid >> 6;
  const int mw   = wv & 3;      // token quarter (16 tokens)
  const int nw   = wv >> 2;     // f-half (16 f) / d-half (128 d)
  const int q    = lane >> 4;
  const int ln   = lane & 15;

  if (tid == 0) {
    int acc = 0;
    #pragma unroll 1
    for (int e = 0; e < NE; e++) { pfx[e] = acc; acc += (counts[e] + 63) >> 6; }
    pfx[NE] = acc;
  }
  __syncthreads();

  // all scheduling scalars forced to SGPR: barriers stay in scalar control flow
  const int U  = __builtin_amdgcn_readfirstlane(pfx[NE] << 5);  // total chunk units
  const int ub = ((blockIdx.x & 7) << 6) | (blockIdx.x >> 3);   // XCD-contiguous (512)
  int       u  = (ub * U) >> 9;                                 // this block's range
  const int u1 = ((ub + 1) * U) >> 9;

  #pragma unroll 1
  while (u < u1) {
    // locate (expert, tile, chunk-range) for unit u
    const int g = u >> 5;                           // global tile id (scalar)
    int ev = 0;
    #pragma unroll 1
    while (pfx[ev + 1] <= g) ev++;
    const int e   = __builtin_amdgcn_readfirstlane(ev);
    const int t   = __builtin_amdgcn_readfirstlane(g - pfx[e]);
    const int c0  = u & 31;
    const int c1  = (32 < c0 + (u1 - u)) ? 32 : (c0 + (u1 - u));
    const int cnt = __builtin_amdgcn_readfirstlane(counts[e]);
    const int t0  = t << 6;
    const unsigned short* wE = wB + (size_t)e * 96 * 8192;
    const int*   el = etok + (size_t)e * TOK;
    const float* ew = ewt  + (size_t)e * TOK;

    if (tid < 64) {
      int gt = t0 + tid;
      lel[tid] = (gt < cnt) ? el[gt] : -1;
      lwt[tid] = (gt < cnt) ? ew[gt] : 0.f;
    }
    __syncthreads();

    // A-fragments: 16 tokens x K=256 in registers (fp32->bf16), 32 VGPR
    bf16x8 xf[8];
    {
      int row = mw*16 + ln;
      int tok = lel[row]; if (tok < 0) tok = 0;
      const float* xr = x + (size_t)tok * DIM;
      #pragma unroll
      for (int k = 0; k < 8; k++) {
        float4 a = *(const float4*)(xr + k*32 + q*8);
        float4 c = *(const float4*)(xr + k*32 + q*8 + 4);
        union { bf16x8 v; unsigned short s[8]; } tt;
        tt.s[0]=f2b(a.x); tt.s[1]=f2b(a.y); tt.s[2]=f2b(a.z); tt.s[3]=f2b(a.w);
        tt.s[4]=f2b(c.x); tt.s[5]=f2b(c.y); tt.s[6]=f2b(c.z); tt.s[7]=f2b(c.w);
        xf[k] = tt.v;
      }
    }

    f32x4 oacc[8];
    #pragma unroll
    for (int nt = 0; nt < 8; nt++) oacc[nt] = (f32x4){0,0,0,0};

    const int S = 3 * (c1 - c0);    // stages this segment (>= 3, scalar)

    // pin the vmcnt baseline (xf loads fully retired), then prime the ring:
    // 3 stages = 6 loads in flight
    asm volatile("s_waitcnt vmcnt(0)" ::: "memory");
    ISSUE_L(0); ISSUE_L(1); ISSUE_L(2);

    f32x4 ga;

    #pragma unroll 1
    for (int c = c0; c < c1; c++) {
      const int sb = 3 * (c - c0);
      // barrier A: stages sb (G), sb+1 (U) arrived; c.D (2 loads) stays in flight
      PWB(2);
      if (sb + 3 < S) ISSUE_L(sb + 3);          // (c+1).G -> slot of (c-1).D
      { const unsigned short* rs = ring[ sb      & 3]; COMP_G(rs); }
      { const unsigned short* rs = ring[(sb + 1) & 3]; COMP_U(rs); }
      // barrier B: stage sb+2 (D) arrived + hs writes visible
      if (sb + 3 < S) {
        PWB(2);                                  // (c+1).G stays in flight
        ISSUE_L(sb + 4);                         // (c+1).U -> slot of c.G
        ISSUE_L(sb + 5);                         // (c+1).D -> slot of c.U
      } else {
        PWB(0);                                  // tail drain
      }
      { const unsigned short* rs = ring[(sb + 2) & 3]; COMP_D(rs); }
    }

    // partial-tile weighted atomic scatter
    #pragma unroll
    for (int nt = 0; nt < 8; nt++) {
      int d = nw*128 + nt*16 + ln;
      #pragma unroll
      for (int rr = 0; rr < 4; rr++) {
        int tl = mw*16 + q*4 + rr;
        int tok = lel[tl];
        if (tok >= 0)
          atomicAdd(&out[(size_t)tok*DIM + d], lwt[tl] * oacc[nt][rr]);
      }
    }
    __syncthreads();   // protect lel/lwt/ring/hs before next segment

    u += c1 - c0;
  }
}

// ========== Fallback expert kernel (fp32 weights, on-the-fly convert) ==========
__global__ __launch_bounds__(512, 2) void expert_mfma5_kernel(
    const float* __restrict__ x,
    const float* __restrict__ wg_, const float* __restrict__ wu_,
    const float* __restrict__ wd_,
    const int* __restrict__ counts,
    const int* __restrict__ etok, const float* __restrict__ ewt,
    float* __restrict__ out)
{
  const int b  = blockIdx.x;
  const int j  = b >> 3;
  const int e  = (b & 7) + 8 * (j & 3);
  const int s0 = j >> 2;
  const int cnt = counts[e];

  __shared__ unsigned short stg[2][16384];
  __shared__ unsigned short hsf[128][72];
  __shared__ int   lel[128];
  __shared__ float lwt[128];

  const int tid  = threadIdx.x;
  const int lane = tid & 63;
  const int wv   = tid >> 6;
  const int mw   = wv & 3;
  const int nw   = wv >> 2;
  const int q    = lane >> 4;
  const int ln   = lane & 15;

  int guOff[4], dOff[4], dRow[4], dFg[4];
  #pragma unroll
  for (int i = 0; i < 4; i++) {
    int G = i*512 + tid;
    int f = G >> 5, gk = G & 31;
    guOff[i] = f*256 + ((gk ^ (f & 7)) << 3);
    int d = G >> 3, fg = G & 7;
    dOff[i] = d*64 + ((fg ^ (d & 7)) << 3);
    dRow[i] = d; dFg[i] = fg;
  }

  const float* wgE = wg_ + (size_t)e * NF * DIM;
  const float* wuE = wu_ + (size_t)e * NF * DIM;
  const float* wdE = wd_ + (size_t)e * DIM * NF;

  const int*   el = etok + (size_t)e * TOK;
  const float* ew = ewt  + (size_t)e * TOK;

  for (int t0 = s0 * 128; t0 < cnt; t0 += 1024) {
    if (tid < 128) {
      int gt = t0 + tid;
      lel[tid] = (gt < cnt) ? el[gt] : -1;
      lwt[tid] = (gt < cnt) ? ew[gt] : 0.f;
    }
    __syncthreads();

    bf16x8 xf[2][8];
    #pragma unroll
    for (int m = 0; m < 2; m++) {
      int row = mw*32 + m*16 + ln;
      int tok = lel[row]; if (tok < 0) tok = 0;
      const float* xr = x + (size_t)tok * DIM;
      #pragma unroll
      for (int k = 0; k < 8; k++) {
        float4 a = *(const float4*)(xr + k*32 + q*8);
        float4 c = *(const float4*)(xr + k*32 + q*8 + 4);
        union { bf16x8 v; unsigned short s[8]; } t;
        t.s[0]=f2b(a.x); t.s[1]=f2b(a.y); t.s[2]=f2b(a.z); t.s[3]=f2b(a.w);
        t.s[4]=f2b(c.x); t.s[5]=f2b(c.y); t.s[6]=f2b(c.z); t.s[7]=f2b(c.w);
        xf[m][k] = t.v;
      }
    }

    f32x4 oacc[8][2];
    #pragma unroll
    for (int nt = 0; nt < 8; nt++) { oacc[nt][0] = (f32x4){0,0,0,0}; oacc[nt][1] = (f32x4){0,0,0,0}; }

    unsigned short* pA = stg[0];
    unsigned short* pB = stg[1];
    float4 r[8];

    {
      const float4* s4 = (const float4*)wgE;
      #pragma unroll
      for (int i = 0; i < 4; i++) { int G = i*512 + tid; r[2*i] = s4[2*G]; r[2*i+1] = s4[2*G+1]; }
      #pragma unroll
      for (int i = 0; i < 4; i++) {
        u16x8 v;
        v[0]=f2b(r[2*i].x);   v[1]=f2b(r[2*i].y);   v[2]=f2b(r[2*i].z);   v[3]=f2b(r[2*i].w);
        v[4]=f2b(r[2*i+1].x); v[5]=f2b(r[2*i+1].y); v[6]=f2b(r[2*i+1].z); v[7]=f2b(r[2*i+1].w);
        *(u16x8*)&pA[guOff[i]] = v;
      }
    }
    __syncthreads();

    f32x4 ga[2][2];

    for (int ch = 0; ch < 16; ch++) {
      {
        const float4* s4 = (const float4*)(wuE + (size_t)ch*16384);
        #pragma unroll
        for (int i = 0; i < 4; i++) { int G = i*512 + tid; r[2*i] = s4[2*G]; r[2*i+1] = s4[2*G+1]; }
      }
      #pragma unroll
      for (int nt = 0; nt < 2; nt++) {
        int fl = nw*32 + nt*16 + ln;
        int rowb = fl*256, xo = fl & 7;
        ga[nt][0] = (f32x4){0,0,0,0}; ga[nt][1] = (f32x4){0,0,0,0};
        #pragma unroll
        for (int kk = 0; kk < 8; kk++) {
          bf16x8 bg = *(const bf16x8*)&pA[rowb + (((kk*4 + q) ^ xo) << 3)];
          ga[nt][0] = __builtin_amdgcn_mfma_f32_16x16x32_bf16(xf[0][kk], bg, ga[nt][0], 0,0,0);
          ga[nt][1] = __builtin_amdgcn_mfma_f32_16x16x32_bf16(xf[1][kk], bg, ga[nt][1], 0,0,0);
        }
      }
      #pragma unroll
      for (int i = 0; i < 4; i++) {
        u16x8 v;
        v[0]=f2b(r[2*i].x);   v[1]=f2b(r[2*i].y);   v[2]=f2b(r[2*i].z);   v[3]=f2b(r[2*i].w);
        v[4]=f2b(r[2*i+1].x); v[5]=f2b(r[2*i+1].y); v[6]=f2b(r[2*i+1].z); v[7]=f2b(r[2*i+1].w);
        *(u16x8*)&pB[guOff[i]] = v;
      }
      __syncthreads();
      { unsigned short* t = pA; pA = pB; pB = t; }

      {
        #pragma unroll
        for (int i = 0; i < 4; i++) {
          const float4* p = (const float4*)(wdE + (size_t)dRow[i]*NF + ch*64 + dFg[i]*8);
          r[2*i] = p[0]; r[2*i+1] = p[1];
        }
      }
      #pragma unroll
      for (int nt = 0; nt < 2; nt++) {
        int fl = nw*32 + nt*16 + ln;
        int rowb = fl*256, xo = fl & 7;
        f32x4 ua0 = (f32x4){0,0,0,0}, ua1 = (f32x4){0,0,0,0};
        #pragma unroll
        for (int kk = 0; kk < 8; kk++) {
          bf16x8 bu = *(const bf16x8*)&pA[rowb + (((kk*4 + q) ^ xo) << 3)];
          ua0 = __builtin_amdgcn_mfma_f32_16x16x32_bf16(xf[0][kk], bu, ua0, 0,0,0);
          ua1 = __builtin_amdgcn_mfma_f32_16x16x32_bf16(xf[1][kk], bu, ua1, 0,0,0);
        }
        #pragma unroll
        for (int rr = 0; rr < 4; rr++) {
          float g0 = ga[nt][0][rr], g1 = ga[nt][1][rr];
          hsf[mw*32      + q*4 + rr][fl] = f2b((g0 / (1.f + __expf(-g0))) * ua0[rr]);
          hsf[mw*32 + 16 + q*4 + rr][fl] = f2b((g1 / (1.f + __expf(-g1))) * ua1[rr]);
        }
      }
      #pragma unroll
      for (int i = 0; i < 4; i++) {
        u16x8 v;
        v[0]=f2b(r[2*i].x);   v[1]=f2b(r[2*i].y);   v[2]=f2b(r[2*i].z);   v[3]=f2b(r[2*i].w);
        v[4]=f2b(r[2*i+1].x); v[5]=f2b(r[2*i+1].y); v[6]=f2b(r[2*i+1].z); v[7]=f2b(r[2*i+1].w);
        *(u16x8*)&pB[dOff[i]] = v;
      }
      __syncthreads();
      { unsigned short* t = pA; pA = pB; pB = t; }

      if (ch < 15) {
        const float4* s4 = (const float4*)(wgE + (size_t)(ch+1)*16384);
        #pragma unroll
        for (int i = 0; i < 4; i++) { int G = i*512 + tid; r[2*i] = s4[2*G]; r[2*i+1] = s4[2*G+1]; }
      }
      #pragma unroll
      for (int kk = 0; kk < 2; kk++) {
        bf16x8 a0 = *(const bf16x8*)&hsf[mw*32      + ln][kk*32 + q*8];
        bf16x8 a1 = *(const bf16x8*)&hsf[mw*32 + 16 + ln][kk*32 + q*8];
        #pragma unroll
        for (int nt = 0; nt < 8; nt++) {
          int d = nw*128 + nt*16 + ln;
          bf16x8 bd = *(const bf16x8*)&pA[d*64 + (((kk*4 + q) ^ (d & 7)) << 3)];
          oacc[nt][0] = __builtin_amdgcn_mfma_f32_16x16x32_bf16(a0, bd, oacc[nt][0], 0,0,0);
          oacc[nt][1] = __builtin_amdgcn_mfma_f32_16x16x32_bf16(a1, bd, oacc[nt][1], 0,0,0);
        }
      }
      if (ch < 15) {
        #pragma unroll
        for (int i = 0; i < 4; i++) {
          u16x8 v;
          v[0]=f2b(r[2*i].x);   v[1]=f2b(r[2*i].y);   v[2]=f2b(r[2*i].z);   v[3]=f2b(r[2*i].w);
          v[4]=f2b(r[2*i+1].x); v[5]=f2b(r[2*i+1].y); v[6]=f2b(r[2*i+1].z); v[7]=f2b(r[2*i+1].w);
          *(u16x8*)&pB[guOff[i]] = v;
        }
      }
      __syncthreads();
      { unsigned short* t = pA; pA = pB; pB = t; }
    }

    #pragma unroll
    for (int nt = 0; nt < 8; nt++) {
      int d = nw*128 + nt*16 + ln;
      #pragma unroll
      for (int m = 0; m < 2; m++)
        #pragma unroll
        for (int rr = 0; rr < 4; rr++) {
          int tl = mw*32 + m*16 + q*4 + rr;
          int tok = lel[tl];
          if (tok >= 0)
            atomicAdd(&out[(size_t)tok*DIM + d], lwt[tl] * oacc[nt][m][rr]);
        }
    }
    __syncthreads();
  }
}

extern "C" void kernel_launch(void* const* d_in, const int* in_sizes, int n_in,
                              void* d_out, int out_size, void* d_ws, size_t ws_size,
                              hipStream_t stream)
{
  const float* x  = (const float*)d_in[0];
  const float* rw = (const float*)d_in[1];
  const float* wg = (const float*)d_in[2];
  const float* wu = (const float*)d_in[3];
  const float* wd = (const float*)d_in[4];
  float* out = (float*)d_out;

  // ws layout: counts[32] | psum[32] | etok[E*T] | ewt[E*T] | ... | wB (48MB @ 4MB)
  int*   counts = (int*)d_ws;
  float* psum   = (float*)((char*)d_ws + 128);
  int*   etok   = (int*)((char*)d_ws + 256);
  float* ewt    = (float*)((char*)d_ws + 256 + (size_t)NE*TOK*4);

  hipMemsetAsync(d_ws, 0, 256, stream);

  const size_t wboff = (size_t)4 << 20;
  const size_t wbsz  = (size_t)NE * 96 * 8192 * 2;   // 48 MB
  if (ws_size >= wboff + wbsz) {
    unsigned short* wB = (unsigned short*)((char*)d_ws + wboff);
    convert_kernel<<<CVT_BLOCKS, 256, 0, stream>>>(wg, wu, wd, wB);
    router_kernel<<<TOK/32, 256, 0, stream>>>(x, rw, counts, psum, etok, ewt, out);
    aux_kernel<<<1, 64, 0, stream>>>(counts, psum, out + (size_t)TOK*DIM);
    expert_mfma11_kernel<<<512, 512, 0, stream>>>(x, wB, counts, etok, ewt, out);
  } else {
    router_kernel<<<TOK/32, 256, 0, stream>>>(x, rw, counts, psum, etok, ewt, out);
    aux_kernel<<<1, 64, 0, stream>>>(counts, psum, out + (size_t)TOK*DIM);
    expert_mfma5_kernel<<<256, 512, 0, stream>>>(x, wg, wu, wd, counts, etok, ewt, out);
  }
}